// Round 13
// baseline (400.022 us; speedup 1.0000x reference)
//
#include <hip/hip_runtime.h>
#include <hip/hip_bf16.h>

#define EPSV 1e-5f

// workspace layout: [wB2][xTp][stats]
#define WB2_ELEMS (2*8*36*128*32)          // [p][nt(8)][kt(36)][nl(128)][kk(32)] bf16
#define WB2_BYTES ((size_t)WB2_ELEMS*2)    // 4,718,592
#define XTP_ELEMS (8*68*68*128)            // padded channels-last x, bf16
#define XTP_BYTES ((size_t)XTP_ELEMS*2)    // 9,469,952
#define STATS_OFF (WB2_BYTES + XTP_BYTES)  // 1024 float2 partials

typedef __attribute__((ext_vector_type(8))) short short8;
typedef __attribute__((ext_vector_type(4))) float f32x4;

__device__ __forceinline__ void gload_lds16(const void* g, void* l) {
    __builtin_amdgcn_global_load_lds(
        (const __attribute__((address_space(1))) void*)g,
        (__attribute__((address_space(3))) void*)l, 16, 0, 0);
}

// ---------------------------------------------------------------------------
// x [8][128][64][64] f32  ->  xTp [8][68][68][128] bf16 (2-px zero halo)
__global__ __launch_bounds__(256) void k_xpad(const float* __restrict__ x,
                                              __hip_bfloat16* __restrict__ xTp) {
    int bh = blockIdx.x; int b = bh >> 6, h = bh & 63;
    __shared__ __hip_bfloat16 tile[64][130];
    int t = threadIdx.x;
#pragma unroll
    for (int i = 0; i < 32; ++i) {
        int e = (i << 8) + t; int w = e & 63; int ci = e >> 6;
        tile[w][ci] = __float2bfloat16(x[(((size_t)(b*128 + ci))*64 + h)*64 + w]);
    }
    __syncthreads();
    __hip_bfloat16* dst = xTp + ((size_t)((b*68 + h + 2)*68 + 2))*128;
#pragma unroll
    for (int i = 0; i < 32; ++i) {
        int e = (i << 8) + t; int ci = e & 127; int w = e >> 7;
        dst[w*128 + ci] = tile[w][ci];
    }
}

// ---------------------------------------------------------------------------
// w_mid [128][16][128][3][3] f32 -> wB2 [p][nt(8)][kt(36)][nl(128)][kk(32)]
__global__ void k_wrepack(const float* __restrict__ w_mid,
                          __hip_bfloat16* __restrict__ wB2) {
    int idx = blockIdx.x * 256 + threadIdx.x;
    if (idx >= WB2_ELEMS) return;
    int kk  = idx & 31;
    int nl  = (idx >> 5) & 127;
    int q   = idx >> 12;             // (p*8+nt)*36 + kt
    int kt  = q % 36;
    int pnt = q / 36;
    int nt  = pnt & 7, p = pnt >> 3;
    int c = ((nt*8 + (nl >> 4)) << 1) + p;
    int m = nl & 15;
    int k = kt*32 + kk;
    int tap = k >> 7, ci = k & 127;
    wB2[idx] = __float2bfloat16(w_mid[((size_t)((c*16 + m)*128 + ci))*9 + tap]);
}

// ---------------------------------------------------------------------------
// Implicit-GEMM conv: BM=128, BN=256, BK=32, 4 waves (2M x 2N), acc 4x8.
// 2 static buffer sets (48 KB LDS -> 3 blocks/CU = 12 waves, R10's proven
// occupancy) with distance-1 counted prefetch. Per step:
//   ISSUE(u+1) -> vmcnt(6) -> barrier -> ds_read+MFMA(u) -> barrier.
// End barrier protects buf[u&1] from iter u+1's ISSUE (WAR). Swizzles = R10.
__global__ __launch_bounds__(256) void k_conv(
    const __hip_bfloat16* __restrict__ xTp,
    const __hip_bfloat16* __restrict__ wB2,
    const float* __restrict__ w_pt,
    const float* __restrict__ b_pt,
    float* __restrict__ y) {
    __shared__ __hip_bfloat16 Alds[2*4096];   // 2 x 8 KB
    __shared__ __hip_bfloat16 Blds[2*8192];   // 2 x 16 KB

    // XCD combo = (p, nt-pair): per-XCD B slice = 576 KB (R12-proven)
    const int combo = blockIdx.x & 7;
    const int p   = combo & 1;
    const int ntp = combo >> 1;          // nt-pair 0..3 (cols ntp*256..+255)
    const int mt  = blockIdx.x >> 3;     // spatial tile 0..255
    const int dil = 1 + p;

    const int t = threadIdx.x;
    const int lane = t & 63;
    const int wave = t >> 6;
    const int wm = wave >> 1, wn = wave & 1;

    const int rsub = t >> 2;                              // staging row (0..63)
    const int ksub = (((t & 3) ^ ((t >> 3) & 3)) << 3);   // src-side swizzled slot

    // A source base pointers (tap center, k-chunk 0) per 64-row pass (R10)
    const __hip_bfloat16* abase0;
    const __hip_bfloat16* abase1;
    {
        int s0 = mt*128 + rsub;
        int s1 = s0 + 64;
        abase0 = xTp + ((size_t)(((s0>>12)*68 + ((s0>>6)&63) + 2)*68 + (s0&63) + 2))*128 + ksub;
        abase1 = xTp + ((size_t)(((s1>>12)*68 + ((s1>>6)&63) + 2)*68 + (s1&63) + 2))*128 + ksub;
    }
    // B source: nt0 = ntp*2 slab; nt1 = +36*4096 elems (R12-proven)
    const __hip_bfloat16* bbase = wB2 + (size_t)p*(8*36*4096)
                                + (size_t)(ntp*2)*(36*4096) + rsub*32 + ksub;

    // staging: 6 x gload_lds per thread per step (A 8 KB + B 16 KB)
#define ISSUE(u, bufi) do {                                                   \
    const int tap_ = (u) >> 2, kc_ = (u) & 3;                                 \
    const int kh_ = tap_/3 - 1, kw_ = tap_%3 - 1;                             \
    const int toff_ = dil*(128*(kh_*68 + kw_)) + kc_*32;                      \
    gload_lds16(abase0 + toff_, (char*)Alds + (bufi)*8192 + t*16);            \
    gload_lds16(abase1 + toff_, (char*)Alds + (bufi)*8192 + 4096 + t*16);     \
    gload_lds16(bbase + (size_t)(u)*4096,                 (char*)Blds + (bufi)*16384 + t*16);         \
    gload_lds16(bbase + (size_t)(u)*4096 + 2048,          (char*)Blds + (bufi)*16384 + 4096 + t*16);  \
    gload_lds16(bbase + (size_t)(u)*4096 + 147456,        (char*)Blds + (bufi)*16384 + 8192 + t*16);  \
    gload_lds16(bbase + (size_t)(u)*4096 + 147456 + 2048, (char*)Blds + (bufi)*16384 + 12288 + t*16); \
  } while (0)

    f32x4 acc[4][8];
#pragma unroll
    for (int i = 0; i < 4; ++i)
#pragma unroll
        for (int j = 0; j < 8; ++j) acc[i][j] = (f32x4){0.f, 0.f, 0.f, 0.f};

    const int lm = lane & 15;
    const int lg = lane >> 4;
    const int sslot = (lg ^ ((lm >> 1) & 3)) << 3;   // read-side swizzled slot
    int aoff[4], boff[8];
#pragma unroll
    for (int i = 0; i < 4; ++i)
        aoff[i] = (wm*64 + i*16 + lm)*32 + sslot;
#pragma unroll
    for (int j = 0; j < 8; ++j)
        boff[j] = (j >> 2)*4096 + (wn*64 + (j & 3)*16 + lm)*32 + sslot;

    // prologue: issue step 0 into buf 0
    ISSUE(0, 0);

#pragma unroll
    for (int u = 0; u < 36; ++u) {
        const int bi = u & 1;
        // issue next step first so 6 loads stay in flight across the wait
        if (u + 1 < 36) {
            ISSUE(u + 1, (u + 1) & 1);
            asm volatile("s_waitcnt vmcnt(6)" ::: "memory");
        } else {
            asm volatile("s_waitcnt vmcnt(0)" ::: "memory");
        }
        __builtin_amdgcn_s_barrier();        // all waves' step-u data visible
        __builtin_amdgcn_sched_barrier(0);
        short8 af[4], bf[8];
#pragma unroll
        for (int i = 0; i < 4; ++i) af[i] = *(const short8*)(Alds + bi*4096 + aoff[i]);
#pragma unroll
        for (int j = 0; j < 8; ++j) bf[j] = *(const short8*)(Blds + bi*8192 + boff[j]);
        __builtin_amdgcn_s_setprio(1);
#pragma unroll
        for (int i = 0; i < 4; ++i)
#pragma unroll
            for (int j = 0; j < 8; ++j)
                acc[i][j] = __builtin_amdgcn_mfma_f32_16x16x32_bf16(
                    af[i], bf[j], acc[i][j], 0, 0, 0);
        __builtin_amdgcn_s_setprio(0);
        __builtin_amdgcn_s_barrier();        // reads of buf bi done (WAR guard)
    }
#undef ISSUE

    // epilogue: leaky -> *w_pt -> reduce over m (16 lanes) -> +b_pt -> y
#pragma unroll
    for (int j = 0; j < 8; ++j) {
        int nt = ntp*2 + (j >> 2);
        int n_g = nt*128 + wn*64 + (j & 3)*16 + lm;
        int c = ((n_g >> 4) << 1) + p;     // uniform across the 16-lane group
        float wp = w_pt[c*16 + lm];        // m == lm
        float bp = b_pt[c];
#pragma unroll
        for (int i = 0; i < 4; ++i) {
#pragma unroll
            for (int r = 0; r < 4; ++r) {
                float v = acc[i][j][r];
                v = v >= 0.f ? v : 0.1f*v;
                v *= wp;
                v += __shfl_xor(v, 1);
                v += __shfl_xor(v, 2);
                v += __shfl_xor(v, 4);
                v += __shfl_xor(v, 8);
                if (lm == 0) {
                    int s = mt*128 + wm*64 + i*16 + lg*4 + r;
                    int b = s >> 12, hw = s & 4095;
                    y[(size_t)(b*128 + c)*4096 + hw] = v + bp;
                }
            }
        }
    }
}

// ---------------------------------------------------------------------------
// per-(b,c)-plane partial sums (float4 loads, no atomics, deterministic)
__global__ __launch_bounds__(256) void k_ystat(const float* __restrict__ y,
                                               float2* __restrict__ partials) {
    int P = blockIdx.x;                 // plane = b*128 + c
    const float4* base = (const float4*)(y + (size_t)P*4096);
    int t = threadIdx.x;
    float s = 0.f, s2 = 0.f;
#pragma unroll
    for (int i = 0; i < 4; ++i) {
        float4 v = base[t + i*256];
        s  += v.x + v.y + v.z + v.w;
        s2 += v.x*v.x + v.y*v.y + v.z*v.z + v.w*v.w;
    }
#pragma unroll
    for (int o = 32; o; o >>= 1) { s += __shfl_down(s, o); s2 += __shfl_down(s2, o); }
    __shared__ float ss[4], ss2[4];
    if ((t & 63) == 0) { ss[t >> 6] = s; ss2[t >> 6] = s2; }
    __syncthreads();
    if (t == 0)
        partials[P] = make_float2(ss[0]+ss[1]+ss[2]+ss[3], ss2[0]+ss2[1]+ss2[2]+ss2[3]);
}

// BN finalize + apply + ReLU. Block covers 256 float4 = quarter of one plane.
__global__ __launch_bounds__(256) void k_bn_apply(float* __restrict__ y,
                                                  const float2* __restrict__ partials,
                                                  const float* __restrict__ gamma,
                                                  const float* __restrict__ beta) {
    int bid = blockIdx.x;
    int c = (bid >> 2) & 127;
    float s = 0.f, s2 = 0.f;
#pragma unroll
    for (int b = 0; b < 8; ++b) {
        float2 pr = partials[b*128 + c];
        s += pr.x; s2 += pr.y;
    }
    float mean = s * (1.f/32768.f);
    float var  = s2 * (1.f/32768.f) - mean*mean;
    float scale = gamma[c] * rsqrtf(var + EPSV);
    float shift = beta[c] - mean*scale;
    float4* y4 = (float4*)y;
    int idx = bid*256 + threadIdx.x;
    float4 v = y4[idx];
    v.x = fmaxf(v.x*scale + shift, 0.f);
    v.y = fmaxf(v.y*scale + shift, 0.f);
    v.z = fmaxf(v.z*scale + shift, 0.f);
    v.w = fmaxf(v.w*scale + shift, 0.f);
    y4[idx] = v;
}

// ---------------------------------------------------------------------------
extern "C" void kernel_launch(void* const* d_in, const int* in_sizes, int n_in,
                              void* d_out, int out_size, void* d_ws, size_t ws_size,
                              hipStream_t stream) {
    const float* x     = (const float*)d_in[0];
    const float* w_mid = (const float*)d_in[1];
    const float* w_pt  = (const float*)d_in[2];
    const float* b_pt  = (const float*)d_in[3];
    const float* gamma = (const float*)d_in[4];
    const float* beta  = (const float*)d_in[5];
    float* y = (float*)d_out;

    __hip_bfloat16* wB2 = (__hip_bfloat16*)d_ws;
    __hip_bfloat16* xTp = (__hip_bfloat16*)((char*)d_ws + WB2_BYTES);
    float2* partials    = (float2*)((char*)d_ws + STATS_OFF);

    hipMemsetAsync(xTp, 0, XTP_BYTES, stream);                  // zero halo
    k_xpad<<<512, 256, 0, stream>>>(x, xTp);
    k_wrepack<<<(WB2_ELEMS + 255) / 256, 256, 0, stream>>>(w_mid, wB2);
    k_conv<<<2048, 256, 0, stream>>>(xTp, wB2, w_pt, b_pt, y);
    k_ystat<<<1024, 256, 0, stream>>>(y, partials);
    k_bn_apply<<<4096, 256, 0, stream>>>(y, partials, gamma, beta);
}

// Round 14
// 255.649 us; speedup vs baseline: 1.5647x; 1.5647x over previous
//
#include <hip/hip_runtime.h>
#include <hip/hip_bf16.h>

#define EPSV 1e-5f

// workspace layout: [wB2][xTp][stats]
#define WB2_ELEMS (2*8*36*128*32)          // [p][nt(8)][kt(36)][nl(128)][kk(32)] bf16
#define WB2_BYTES ((size_t)WB2_ELEMS*2)    // 4,718,592
#define XTP_ELEMS (8*68*68*128)            // padded channels-last x, bf16
#define XTP_BYTES ((size_t)XTP_ELEMS*2)    // 9,469,952
#define STATS_OFF (WB2_BYTES + XTP_BYTES)  // 1024 float2 partials

// k_conv dynamic LDS: 3 A-bufs (8 KB) + 3 B-bufs (16 KB) = 73,728 B
#define CONV_LDS_BYTES (3*8192 + 3*16384)

typedef __attribute__((ext_vector_type(8))) short short8;
typedef __attribute__((ext_vector_type(4))) float f32x4;

__device__ __forceinline__ void gload_lds16(const void* g, void* l) {
    __builtin_amdgcn_global_load_lds(
        (const __attribute__((address_space(1))) void*)g,
        (__attribute__((address_space(3))) void*)l, 16, 0, 0);
}

// ---------------------------------------------------------------------------
// x [8][128][64][64] f32  ->  xTp [8][68][68][128] bf16 (2-px zero halo)
__global__ __launch_bounds__(256) void k_xpad(const float* __restrict__ x,
                                              __hip_bfloat16* __restrict__ xTp) {
    int bh = blockIdx.x; int b = bh >> 6, h = bh & 63;
    __shared__ __hip_bfloat16 tile[64][130];
    int t = threadIdx.x;
#pragma unroll
    for (int i = 0; i < 32; ++i) {
        int e = (i << 8) + t; int w = e & 63; int ci = e >> 6;
        tile[w][ci] = __float2bfloat16(x[(((size_t)(b*128 + ci))*64 + h)*64 + w]);
    }
    __syncthreads();
    __hip_bfloat16* dst = xTp + ((size_t)((b*68 + h + 2)*68 + 2))*128;
#pragma unroll
    for (int i = 0; i < 32; ++i) {
        int e = (i << 8) + t; int ci = e & 127; int w = e >> 7;
        dst[w*128 + ci] = tile[w][ci];
    }
}

// ---------------------------------------------------------------------------
// w_mid [128][16][128][3][3] f32 -> wB2 [p][nt(8)][kt(36)][nl(128)][kk(32)]
__global__ void k_wrepack(const float* __restrict__ w_mid,
                          __hip_bfloat16* __restrict__ wB2) {
    int idx = blockIdx.x * 256 + threadIdx.x;
    if (idx >= WB2_ELEMS) return;
    int kk  = idx & 31;
    int nl  = (idx >> 5) & 127;
    int q   = idx >> 12;             // (p*8+nt)*36 + kt
    int kt  = q % 36;
    int pnt = q / 36;
    int nt  = pnt & 7, p = pnt >> 3;
    int c = ((nt*8 + (nl >> 4)) << 1) + p;
    int m = nl & 15;
    int k = kt*32 + kk;
    int tap = k >> 7, ci = k & 127;
    wB2[idx] = __float2bfloat16(w_mid[((size_t)((c*16 + m)*128 + ci))*9 + tap]);
}

// ---------------------------------------------------------------------------
// Implicit-GEMM conv: R12 structure (BM=128, BN=256, acc 4x8, 3 rotating
// buffer sets, counted vmcnt(6), distance-2, one barrier/step) with
// __launch_bounds__(256, 2): forces arch-VGPR <= 128 so arch+AGPR(128)
// <= 256/wave -> 2 waves/SIMD -> 2 blocks/CU co-resident (the R13 post-
// mortem showed the unified RF, not LDS, was capping occupancy at 1 block).
__global__ __launch_bounds__(256, 2) void k_conv(
    const __hip_bfloat16* __restrict__ xTp,
    const __hip_bfloat16* __restrict__ wB2,
    const float* __restrict__ w_pt,
    const float* __restrict__ b_pt,
    float* __restrict__ y) {
    extern __shared__ char smem[];
    __hip_bfloat16* Alds = (__hip_bfloat16*)smem;              // 3 x 8 KB
    __hip_bfloat16* Blds = (__hip_bfloat16*)(smem + 3*8192);   // 3 x 16 KB

    // XCD combo = (p, nt-pair): per-XCD B slice = 576 KB (R12-proven)
    const int combo = blockIdx.x & 7;
    const int p   = combo & 1;
    const int ntp = combo >> 1;          // nt-pair 0..3 (cols ntp*256..+255)
    const int mt  = blockIdx.x >> 3;     // spatial tile 0..255
    const int dil = 1 + p;

    const int t = threadIdx.x;
    const int lane = t & 63;
    const int wave = t >> 6;
    const int wm = wave >> 1, wn = wave & 1;

    const int rsub = t >> 2;                              // staging row (0..63)
    const int ksub = (((t & 3) ^ ((t >> 3) & 3)) << 3);   // src-side swizzled slot

    // A source base pointers (tap center, k-chunk 0) per 64-row pass (R10)
    const __hip_bfloat16* abase0;
    const __hip_bfloat16* abase1;
    {
        int s0 = mt*128 + rsub;
        int s1 = s0 + 64;
        abase0 = xTp + ((size_t)(((s0>>12)*68 + ((s0>>6)&63) + 2)*68 + (s0&63) + 2))*128 + ksub;
        abase1 = xTp + ((size_t)(((s1>>12)*68 + ((s1>>6)&63) + 2)*68 + (s1&63) + 2))*128 + ksub;
    }
    // B source: nt0 = ntp*2 slab; nt1 = +36*4096 elems (R12-proven)
    const __hip_bfloat16* bbase = wB2 + (size_t)p*(8*36*4096)
                                + (size_t)(ntp*2)*(36*4096) + rsub*32 + ksub;

    // staging: 6 x gload_lds per thread per step (A 8 KB + B 16 KB)
#define ISSUE(u, bufi) do {                                                   \
    const int tap_ = (u) >> 2, kc_ = (u) & 3;                                 \
    const int kh_ = tap_/3 - 1, kw_ = tap_%3 - 1;                             \
    const int toff_ = dil*(128*(kh_*68 + kw_)) + kc_*32;                      \
    gload_lds16(abase0 + toff_, (char*)Alds + (bufi)*8192 + t*16);            \
    gload_lds16(abase1 + toff_, (char*)Alds + (bufi)*8192 + 4096 + t*16);     \
    gload_lds16(bbase + (size_t)(u)*4096,                 (char*)Blds + (bufi)*16384 + t*16);         \
    gload_lds16(bbase + (size_t)(u)*4096 + 2048,          (char*)Blds + (bufi)*16384 + 4096 + t*16);  \
    gload_lds16(bbase + (size_t)(u)*4096 + 147456,        (char*)Blds + (bufi)*16384 + 8192 + t*16);  \
    gload_lds16(bbase + (size_t)(u)*4096 + 147456 + 2048, (char*)Blds + (bufi)*16384 + 12288 + t*16); \
  } while (0)

    f32x4 acc[4][8];
#pragma unroll
    for (int i = 0; i < 4; ++i)
#pragma unroll
        for (int j = 0; j < 8; ++j) acc[i][j] = (f32x4){0.f, 0.f, 0.f, 0.f};

    const int lm = lane & 15;
    const int lg = lane >> 4;
    const int sslot = (lg ^ ((lm >> 1) & 3)) << 3;   // read-side swizzled slot
    int aoff[4], boff[8];
#pragma unroll
    for (int i = 0; i < 4; ++i)
        aoff[i] = (wm*64 + i*16 + lm)*32 + sslot;
#pragma unroll
    for (int j = 0; j < 8; ++j)
        boff[j] = (j >> 2)*4096 + (wn*64 + (j & 3)*16 + lm)*32 + sslot;

    // prologue: issue steps 0 and 1
    ISSUE(0, 0);
    ISSUE(1, 1);

#pragma unroll
    for (int u = 0; u < 36; ++u) {
        const int bi  = u % 3;
        const int bi2 = (u + 2) % 3;
        // wait for step u's 6 loads (leave step u+1's 6 in flight); tail: drain
        if (u < 35) asm volatile("s_waitcnt vmcnt(6)" ::: "memory");
        else        asm volatile("s_waitcnt vmcnt(0)" ::: "memory");
        __builtin_amdgcn_s_barrier();
        __builtin_amdgcn_sched_barrier(0);
        if (u + 2 < 36) ISSUE(u + 2, bi2);
        short8 af[4], bf[8];
#pragma unroll
        for (int i = 0; i < 4; ++i) af[i] = *(const short8*)(Alds + bi*4096 + aoff[i]);
#pragma unroll
        for (int j = 0; j < 8; ++j) bf[j] = *(const short8*)(Blds + bi*8192 + boff[j]);
        __builtin_amdgcn_s_setprio(1);
#pragma unroll
        for (int i = 0; i < 4; ++i)
#pragma unroll
            for (int j = 0; j < 8; ++j)
                acc[i][j] = __builtin_amdgcn_mfma_f32_16x16x32_bf16(
                    af[i], bf[j], acc[i][j], 0, 0, 0);
        __builtin_amdgcn_s_setprio(0);
    }
#undef ISSUE

    // epilogue: leaky -> *w_pt -> reduce over m (16 lanes) -> +b_pt -> y
#pragma unroll
    for (int j = 0; j < 8; ++j) {
        int nt = ntp*2 + (j >> 2);
        int n_g = nt*128 + wn*64 + (j & 3)*16 + lm;
        int c = ((n_g >> 4) << 1) + p;     // uniform across the 16-lane group
        float wp = w_pt[c*16 + lm];        // m == lm
        float bp = b_pt[c];
#pragma unroll
        for (int i = 0; i < 4; ++i) {
#pragma unroll
            for (int r = 0; r < 4; ++r) {
                float v = acc[i][j][r];
                v = v >= 0.f ? v : 0.1f*v;
                v *= wp;
                v += __shfl_xor(v, 1);
                v += __shfl_xor(v, 2);
                v += __shfl_xor(v, 4);
                v += __shfl_xor(v, 8);
                if (lm == 0) {
                    int s = mt*128 + wm*64 + i*16 + lg*4 + r;
                    int b = s >> 12, hw = s & 4095;
                    y[(size_t)(b*128 + c)*4096 + hw] = v + bp;
                }
            }
        }
    }
}

// ---------------------------------------------------------------------------
// per-(b,c)-plane partial sums (float4 loads, no atomics, deterministic)
__global__ __launch_bounds__(256) void k_ystat(const float* __restrict__ y,
                                               float2* __restrict__ partials) {
    int P = blockIdx.x;                 // plane = b*128 + c
    const float4* base = (const float4*)(y + (size_t)P*4096);
    int t = threadIdx.x;
    float s = 0.f, s2 = 0.f;
#pragma unroll
    for (int i = 0; i < 4; ++i) {
        float4 v = base[t + i*256];
        s  += v.x + v.y + v.z + v.w;
        s2 += v.x*v.x + v.y*v.y + v.z*v.z + v.w*v.w;
    }
#pragma unroll
    for (int o = 32; o; o >>= 1) { s += __shfl_down(s, o); s2 += __shfl_down(s2, o); }
    __shared__ float ss[4], ss2[4];
    if ((t & 63) == 0) { ss[t >> 6] = s; ss2[t >> 6] = s2; }
    __syncthreads();
    if (t == 0)
        partials[P] = make_float2(ss[0]+ss[1]+ss[2]+ss[3], ss2[0]+ss2[1]+ss2[2]+ss2[3]);
}

// BN finalize + apply + ReLU. Block covers 256 float4 = quarter of one plane.
__global__ __launch_bounds__(256) void k_bn_apply(float* __restrict__ y,
                                                  const float2* __restrict__ partials,
                                                  const float* __restrict__ gamma,
                                                  const float* __restrict__ beta) {
    int bid = blockIdx.x;
    int c = (bid >> 2) & 127;
    float s = 0.f, s2 = 0.f;
#pragma unroll
    for (int b = 0; b < 8; ++b) {
        float2 pr = partials[b*128 + c];
        s += pr.x; s2 += pr.y;
    }
    float mean = s * (1.f/32768.f);
    float var  = s2 * (1.f/32768.f) - mean*mean;
    float scale = gamma[c] * rsqrtf(var + EPSV);
    float shift = beta[c] - mean*scale;
    float4* y4 = (float4*)y;
    int idx = bid*256 + threadIdx.x;
    float4 v = y4[idx];
    v.x = fmaxf(v.x*scale + shift, 0.f);
    v.y = fmaxf(v.y*scale + shift, 0.f);
    v.z = fmaxf(v.z*scale + shift, 0.f);
    v.w = fmaxf(v.w*scale + shift, 0.f);
    y4[idx] = v;
}

// ---------------------------------------------------------------------------
extern "C" void kernel_launch(void* const* d_in, const int* in_sizes, int n_in,
                              void* d_out, int out_size, void* d_ws, size_t ws_size,
                              hipStream_t stream) {
    const float* x     = (const float*)d_in[0];
    const float* w_mid = (const float*)d_in[1];
    const float* w_pt  = (const float*)d_in[2];
    const float* b_pt  = (const float*)d_in[3];
    const float* gamma = (const float*)d_in[4];
    const float* beta  = (const float*)d_in[5];
    float* y = (float*)d_out;

    __hip_bfloat16* wB2 = (__hip_bfloat16*)d_ws;
    __hip_bfloat16* xTp = (__hip_bfloat16*)((char*)d_ws + WB2_BYTES);
    float2* partials    = (float2*)((char*)d_ws + STATS_OFF);

    // opt in to >64 KB dynamic LDS for k_conv (host-side, graph-capture-safe)
    (void)hipFuncSetAttribute((const void*)k_conv,
                              hipFuncAttributeMaxDynamicSharedMemorySize,
                              CONV_LDS_BYTES);

    hipMemsetAsync(xTp, 0, XTP_BYTES, stream);                  // zero halo
    k_xpad<<<512, 256, 0, stream>>>(x, xTp);
    k_wrepack<<<(WB2_ELEMS + 255) / 256, 256, 0, stream>>>(w_mid, wB2);
    k_conv<<<2048, 256, CONV_LDS_BYTES, stream>>>(xTp, wB2, w_pt, b_pt, y);
    k_ystat<<<1024, 256, 0, stream>>>(y, partials);
    k_bn_apply<<<4096, 256, 0, stream>>>(y, partials, gamma, beta);
}